// Round 1
// baseline (655.585 us; speedup 1.0000x reference)
//
#include <hip/hip_runtime.h>
#include <math.h>

// ChunkedSurpriseGatedSSD on MI355X — round 1: correct fp32 phase-decomposed design.
//
// Key identity: h_prev - decay_prev*h_before == h_contrib(c-1), so
// err(c) = w^T M w / (N*P) with M = (B B^T) o (X X^T) (decay-independent) and
// w_t = exp(ds*(S63 - S_t)).  Gate chain depends on data only through M and the
// scalar ds chain -> precompute err on a 64-point ds-grid per (b,h,chunk), walk
// the sequential chain with one wave (cubic interpolation, ~1e-5 rel error).

#define CSZ 64      // chunk size
#define NCH 64      // number of chunks
#define NHD 16      // heads
#define PD  64      // head dim
#define ND  128     // state dim
#define BHN 32      // B*H
#define NTILES 2048 // BHN*NCH
#define GGRID 64    // ds grid points
#define SEQ 4096

// ws layout in floats
#define WS_S   0                  // S cumsum: [tile][t]  (131072)
#define WS_EG  131072             // err_grid: [c][g][bh] (131072)
#define WS_DS  262144             // ds[c] (64)
#define WS_HC  262400             // h_contrib -> h_prev: [tile][n][p] (16777216)

// ---------------- K1: Gram matrices + err grid + cumsum S ----------------
__global__ __launch_bounds__(256) void k_prep(
    const float* __restrict__ X, const float* __restrict__ A,
    const float* __restrict__ Bm, float* __restrict__ ws)
{
  __shared__ float Bs[CSZ][ND+1];
  __shared__ float Xs[CSZ][PD+1];
  __shared__ float Ms[CSZ][CSZ+1];
  __shared__ float Us[GGRID][CSZ+1];
  __shared__ float Sl[CSZ];
  __shared__ float Zl[CSZ];

  const int tile = blockIdx.x;
  const int c  = tile & 63;
  const int bh = tile >> 6;
  const int b = bh >> 4, h = bh & 15;
  const int tid = threadIdx.x;

  if (tid < CSZ) Sl[tid] = A[(size_t)(b*SEQ + c*CSZ + tid)*NHD + h];
  __syncthreads();
  if (tid == 0) {
    float acc = 0.f;
    #pragma unroll 1
    for (int t = 0; t < CSZ; ++t) { acc += Sl[t]; Sl[t] = acc; }
  }
  __syncthreads();
  if (tid < CSZ) {
    float s63 = Sl[CSZ-1];
    Zl[tid] = s63 - Sl[tid];
    ws[WS_S + tile*CSZ + tid] = Sl[tid];
  }
  {
    const float* Bbase = Bm + ((size_t)(b*SEQ + c*CSZ)*NHD + h)*ND;
    #pragma unroll
    for (int q = 0; q < 8; ++q) {
      int lin = q*256 + tid;
      int t = lin >> 5, pc = lin & 31;
      float4 v = *(const float4*)(Bbase + (size_t)t*(NHD*ND) + pc*4);
      Bs[t][pc*4+0]=v.x; Bs[t][pc*4+1]=v.y; Bs[t][pc*4+2]=v.z; Bs[t][pc*4+3]=v.w;
    }
    const float* Xbase = X + ((size_t)(b*SEQ + c*CSZ)*NHD + h)*PD;
    #pragma unroll
    for (int q = 0; q < 4; ++q) {
      int lin = q*256 + tid;
      int t = lin >> 4, pc = lin & 15;
      float4 v = *(const float4*)(Xbase + (size_t)t*(NHD*PD) + pc*4);
      Xs[t][pc*4+0]=v.x; Xs[t][pc*4+1]=v.y; Xs[t][pc*4+2]=v.z; Xs[t][pc*4+3]=v.w;
    }
  }
  __syncthreads();

  const int i0 = (tid >> 4)*4, j0 = (tid & 15)*4;
  float gb[4][4] = {}; float gx[4][4] = {};
  for (int k = 0; k < ND; ++k) {
    float av[4], bv[4];
    #pragma unroll
    for (int r = 0; r < 4; ++r) { av[r] = Bs[i0+r][k]; bv[r] = Bs[j0+r][k]; }
    #pragma unroll
    for (int r = 0; r < 4; ++r)
      #pragma unroll
      for (int q = 0; q < 4; ++q) gb[r][q] += av[r]*bv[q];
  }
  for (int k = 0; k < PD; ++k) {
    float av[4], bv[4];
    #pragma unroll
    for (int r = 0; r < 4; ++r) { av[r] = Xs[i0+r][k]; bv[r] = Xs[j0+r][k]; }
    #pragma unroll
    for (int r = 0; r < 4; ++r)
      #pragma unroll
      for (int q = 0; q < 4; ++q) gx[r][q] += av[r]*bv[q];
  }
  #pragma unroll
  for (int r = 0; r < 4; ++r)
    #pragma unroll
    for (int q = 0; q < 4; ++q)
      Ms[i0+r][j0+q] = gb[r][q]*gx[r][q]*(1.0f/8192.0f);

  #pragma unroll
  for (int q = 0; q < 16; ++q) {
    int idx = q*256 + tid;
    int g = idx >> 6, t = idx & 63;
    Us[g][t] = expf(((float)g*(1.0f/63.0f))*Zl[t]);
  }
  __syncthreads();

  const int g = tid >> 2, qq = tid & 3;
  float acc = 0.f;
  for (int t = qq*16; t < qq*16+16; ++t) {
    float inner = 0.f;
    #pragma unroll 4
    for (int s = 0; s < CSZ; ++s) inner += Ms[t][s]*Us[g][s];
    acc += Us[g][t]*inner;
  }
  acc += __shfl_xor(acc, 1);
  acc += __shfl_xor(acc, 2);
  if (qq == 0) ws[WS_EG + (c*GGRID + g)*BHN + bh] = acc;
}

// ---------------- K2: sequential gate chain (one wave) ----------------
__global__ __launch_bounds__(64) void k_gate(
    const float* __restrict__ l2ab, const float* __restrict__ l2b,
    const float* __restrict__ sema, float* __restrict__ ws)
{
  const int lane = threadIdx.x;
  const int h = lane & 15;
  float ab = 0.f, bt = 1.f, ema = 0.f;
  if (lane < NHD) {
    float la = fminf(fmaxf(l2ab[lane], -3.32f), -0.015f);
    ab = 1.0f - exp2f(la);
    float lb = fminf(fmaxf(l2b[lane], -2.0f), 2.0f);
    bt = exp2f(lb);
    ema = sema[lane];
  }
  const float ab_bh = __shfl(ab, h);
  const float bt_bh = __shfl(bt, h);
  float ds_prev = 1.0f;
  if (lane == 0) ws[WS_DS + 0] = 1.0f;
  const float* EG = ws + WS_EG;
  for (int c = 1; c < NCH; ++c) {
    const int j = c - 1;
    float x = ds_prev * 63.0f;
    int ib = (int)floorf(x);
    ib = max(1, min(61, ib));
    float u = x - (float)ib;
    float err = 0.f;
    if (lane < BHN) {
      const float* p = EG + ((size_t)j*GGRID + (ib-1))*BHN + lane;
      float ym1 = p[0], y0 = p[32], y1 = p[64], y2 = p[96];
      err = ym1*(u*(u-1.f)*(u-2.f))*(-1.f/6.f)
          + y0 *((u+1.f)*(u-1.f)*(u-2.f))*(0.5f)
          + y1 *((u+1.f)*u*(u-2.f))*(-0.5f)
          + y2 *((u+1.f)*u*(u-1.f))*(1.f/6.f);
    }
    float e0 = __shfl(err, h);
    float e1 = __shfl(err, 16 + h);
    float ema_new = 0.99f*ema + 0.01f*0.5f*(e0 + e1); // valid on lanes<16
    float emv = __shfl(ema_new, h);
    float oma = 0.f;
    if (lane < BHN) {
      float normalized = err / (emv + 1e-6f);
      float boost = fmaxf(tanhf(bt_bh*normalized), 0.f);
      float alpha = ab_bh + (1.f - ab_bh)*boost;
      alpha = fminf(fmaxf(alpha, 0.01f), 0.999f);
      oma = 1.f - alpha;
    }
    float s = oma;
    s += __shfl_xor(s, 1);  s += __shfl_xor(s, 2);  s += __shfl_xor(s, 4);
    s += __shfl_xor(s, 8);  s += __shfl_xor(s, 16);
    float ds = __shfl(s, 0) * (1.0f/32.0f);
    if (lane < NHD) ema = ema_new;
    if (lane == 0) ws[WS_DS + c] = ds;
    ds_prev = ds;
  }
}

// ---------------- K3: CB, Y_intra, h_contrib ----------------
__global__ __launch_bounds__(256) void k_chunk(
    const float* __restrict__ X, const float* __restrict__ Bm,
    const float* __restrict__ Cm, float* __restrict__ ws,
    float* __restrict__ Y)
{
  __shared__ float Bs[CSZ][ND+1];
  __shared__ float Cs[CSZ][ND+1];
  __shared__ float Xs[CSZ][PD+1];
  __shared__ float Es[CSZ][CSZ+1];
  __shared__ float Acs[CSZ];
  __shared__ float Wl[CSZ];

  const int tile = blockIdx.x;
  const int c  = tile & 63;
  const int bh = tile >> 6;
  const int b = bh >> 4, h = bh & 15;
  const int tid = threadIdx.x;

  const float dsc = ws[WS_DS + c];
  if (tid < CSZ) {
    float sv  = ws[WS_S + tile*CSZ + tid];
    float s63 = ws[WS_S + tile*CSZ + 63];
    Acs[tid] = dsc*sv;
    Wl[tid]  = expf(dsc*(s63 - sv));
  }
  {
    const float* Bbase = Bm + ((size_t)(b*SEQ + c*CSZ)*NHD + h)*ND;
    const float* Cbase = Cm + ((size_t)(b*SEQ + c*CSZ)*NHD + h)*ND;
    #pragma unroll
    for (int q = 0; q < 8; ++q) {
      int lin = q*256 + tid;
      int t = lin >> 5, pc = lin & 31;
      float4 v = *(const float4*)(Bbase + (size_t)t*(NHD*ND) + pc*4);
      Bs[t][pc*4+0]=v.x; Bs[t][pc*4+1]=v.y; Bs[t][pc*4+2]=v.z; Bs[t][pc*4+3]=v.w;
      float4 w = *(const float4*)(Cbase + (size_t)t*(NHD*ND) + pc*4);
      Cs[t][pc*4+0]=w.x; Cs[t][pc*4+1]=w.y; Cs[t][pc*4+2]=w.z; Cs[t][pc*4+3]=w.w;
    }
    const float* Xbase = X + ((size_t)(b*SEQ + c*CSZ)*NHD + h)*PD;
    #pragma unroll
    for (int q = 0; q < 4; ++q) {
      int lin = q*256 + tid;
      int t = lin >> 4, pc = lin & 15;
      float4 v = *(const float4*)(Xbase + (size_t)t*(NHD*PD) + pc*4);
      Xs[t][pc*4+0]=v.x; Xs[t][pc*4+1]=v.y; Xs[t][pc*4+2]=v.z; Xs[t][pc*4+3]=v.w;
    }
  }
  __syncthreads();

  const int i0 = (tid >> 4)*4, j0 = (tid & 15)*4;
  {
    float acc[4][4] = {};
    for (int n = 0; n < ND; ++n) {
      float av[4], bv[4];
      #pragma unroll
      for (int r = 0; r < 4; ++r) { av[r] = Cs[i0+r][n]; bv[r] = Bs[j0+r][n]; }
      #pragma unroll
      for (int r = 0; r < 4; ++r)
        #pragma unroll
        for (int q = 0; q < 4; ++q) acc[r][q] += av[r]*bv[q];
    }
    #pragma unroll
    for (int r = 0; r < 4; ++r) {
      int i = i0 + r;
      #pragma unroll
      for (int q = 0; q < 4; ++q) {
        int j = j0 + q;
        Es[i][j] = (i >= j) ? expf(Acs[i]-Acs[j])*acc[r][q] : 0.f;
      }
    }
  }
  __syncthreads();

  {
    float ya[4][4] = {};
    for (int j = 0; j < CSZ; ++j) {
      float ev[4], xv[4];
      #pragma unroll
      for (int r = 0; r < 4; ++r) { ev[r] = Es[i0+r][j]; xv[r] = Xs[j][j0+r]; }
      #pragma unroll
      for (int r = 0; r < 4; ++r)
        #pragma unroll
        for (int q = 0; q < 4; ++q) ya[r][q] += ev[r]*xv[q];
    }
    float* Ybase = Y + ((size_t)(b*SEQ + c*CSZ)*NHD + h)*PD;
    #pragma unroll
    for (int r = 0; r < 4; ++r)
      *(float4*)(Ybase + (size_t)(i0+r)*(NHD*PD) + j0) =
          make_float4(ya[r][0], ya[r][1], ya[r][2], ya[r][3]);
  }

  {
    const int n0 = (tid >> 3)*4, p0 = (tid & 7)*8;
    float hc[4][8] = {};
    for (int t = 0; t < CSZ; ++t) {
      float wt = Wl[t];
      float av[4], xv[8];
      #pragma unroll
      for (int r = 0; r < 4; ++r) av[r] = Bs[t][n0+r];
      #pragma unroll
      for (int m = 0; m < 8; ++m) xv[m] = Xs[t][p0+m]*wt;
      #pragma unroll
      for (int r = 0; r < 4; ++r)
        #pragma unroll
        for (int m = 0; m < 8; ++m) hc[r][m] += av[r]*xv[m];
    }
    float* hcp = ws + WS_HC + (size_t)tile*(ND*PD);
    #pragma unroll
    for (int r = 0; r < 4; ++r) {
      *(float4*)(hcp + (n0+r)*PD + p0)     = make_float4(hc[r][0],hc[r][1],hc[r][2],hc[r][3]);
      *(float4*)(hcp + (n0+r)*PD + p0 + 4) = make_float4(hc[r][4],hc[r][5],hc[r][6],hc[r][7]);
    }
  }
}

// ---------------- K4: h-state scan (in place: h_contrib -> h_prev) ----------------
__global__ __launch_bounds__(256) void k_scan(float* __restrict__ ws)
{
  __shared__ float dtbl[NCH];
  const int bh = blockIdx.x >> 3, part = blockIdx.x & 7;
  const int tid = threadIdx.x;
  if (tid < NCH) {
    float s63 = ws[WS_S + (bh*NCH + tid)*CSZ + 63];
    dtbl[tid] = expf(ws[WS_DS + tid]*s63);
  }
  __syncthreads();
  float* base = ws + WS_HC + (size_t)bh*(NCH*ND*PD) + part*1024 + tid*4;
  float4 h4 = make_float4(0.f, 0.f, 0.f, 0.f);
  #pragma unroll 1
  for (int c = 0; c < NCH; ++c) {
    float4* p = (float4*)(base + (size_t)c*(ND*PD));
    float4 v = *p;
    *p = h4;                       // h_prev(c)
    float dt = dtbl[c];
    h4.x = dt*h4.x + v.x;  h4.y = dt*h4.y + v.y;
    h4.z = dt*h4.z + v.z;  h4.w = dt*h4.w + v.w;
  }
}

// ---------------- K5: Y += dfs o (C @ h_prev) ----------------
__global__ __launch_bounds__(256) void k_inter(
    const float* __restrict__ Cm, float* __restrict__ ws,
    float* __restrict__ Y)
{
  __shared__ float Cs[CSZ][ND+1];
  __shared__ float HPs[ND][PD+1];
  __shared__ float Dfs[CSZ];

  const int tile = blockIdx.x;
  const int c  = tile & 63;
  const int bh = tile >> 6;
  const int b = bh >> 4, h = bh & 15;
  const int tid = threadIdx.x;

  const float dsc = ws[WS_DS + c];
  if (tid < CSZ) Dfs[tid] = expf(dsc*ws[WS_S + tile*CSZ + tid]);
  {
    const float* Cbase = Cm + ((size_t)(b*SEQ + c*CSZ)*NHD + h)*ND;
    #pragma unroll
    for (int q = 0; q < 8; ++q) {
      int lin = q*256 + tid;
      int t = lin >> 5, pc = lin & 31;
      float4 w = *(const float4*)(Cbase + (size_t)t*(NHD*ND) + pc*4);
      Cs[t][pc*4+0]=w.x; Cs[t][pc*4+1]=w.y; Cs[t][pc*4+2]=w.z; Cs[t][pc*4+3]=w.w;
    }
    const float* hp = ws + WS_HC + (size_t)tile*(ND*PD);
    #pragma unroll
    for (int q = 0; q < 8; ++q) {
      int lin = q*256 + tid;
      int n = lin >> 4, pc = lin & 15;
      float4 v = *(const float4*)(hp + (size_t)lin*4);
      HPs[n][pc*4+0]=v.x; HPs[n][pc*4+1]=v.y; HPs[n][pc*4+2]=v.z; HPs[n][pc*4+3]=v.w;
    }
  }
  __syncthreads();

  const int i0 = (tid >> 4)*4, j0 = (tid & 15)*4;
  float acc[4][4] = {};
  for (int n = 0; n < ND; ++n) {
    float av[4], bv[4];
    #pragma unroll
    for (int r = 0; r < 4; ++r) { av[r] = Cs[i0+r][n]; bv[r] = HPs[n][j0+r]; }
    #pragma unroll
    for (int r = 0; r < 4; ++r)
      #pragma unroll
      for (int q = 0; q < 4; ++q) acc[r][q] += av[r]*bv[q];
  }
  float* Ybase = Y + ((size_t)(b*SEQ + c*CSZ)*NHD + h)*PD;
  #pragma unroll
  for (int r = 0; r < 4; ++r) {
    float d = Dfs[i0+r];
    float4* p = (float4*)(Ybase + (size_t)(i0+r)*(NHD*PD) + j0);
    float4 y = *p;
    y.x += d*acc[r][0]; y.y += d*acc[r][1];
    y.z += d*acc[r][2]; y.w += d*acc[r][3];
    *p = y;
  }
}

extern "C" void kernel_launch(void* const* d_in, const int* in_sizes, int n_in,
                              void* d_out, int out_size, void* d_ws, size_t ws_size,
                              hipStream_t stream) {
  const float* X    = (const float*)d_in[0];
  const float* A    = (const float*)d_in[1];
  const float* Bm   = (const float*)d_in[2];
  const float* Cm   = (const float*)d_in[3];
  const float* l2ab = (const float*)d_in[4];
  const float* l2b  = (const float*)d_in[5];
  const float* sema = (const float*)d_in[6];
  float* Y  = (float*)d_out;
  float* ws = (float*)d_ws;

  hipLaunchKernelGGL(k_prep,  dim3(NTILES), dim3(256), 0, stream, X, A, Bm, ws);
  hipLaunchKernelGGL(k_gate,  dim3(1),      dim3(64),  0, stream, l2ab, l2b, sema, ws);
  hipLaunchKernelGGL(k_chunk, dim3(NTILES), dim3(256), 0, stream, X, Bm, Cm, ws, Y);
  hipLaunchKernelGGL(k_scan,  dim3(256),    dim3(256), 0, stream, ws);
  hipLaunchKernelGGL(k_inter, dim3(NTILES), dim3(256), 0, stream, Cm, ws, Y);
}

// Round 2
// 535.178 us; speedup vs baseline: 1.2250x; 1.2250x over previous
//
#include <hip/hip_runtime.h>
#include <math.h>

// ChunkedSurpriseGatedSSD on MI355X — round 2: vectorized LDS (ds_read_b128),
// k_prep split into k_gram + k_errgrid for occupancy + issue-rate.
//
// Identity: h_prev - decay_prev*h_before == h_contrib(c-1) =>
// err(c) = u^T M u / (N*P), M = (B B^T) o (X X^T) (decay-independent),
// u_t = exp(ds*(S63-S_t)). Gate chain walked by one wave over a 64-point
// ds-grid of err (cubic interp, ~1e-5 rel).

#define CSZ 64
#define NCH 64
#define NHD 16
#define PD  64
#define ND  128
#define BHN 32
#define NTILES 2048
#define GGRID 64
#define SEQ 4096

// ws layout in floats
#define WS_S   0                  // S cumsum: [tile][t]  (131072)
#define WS_EG  131072             // err_grid: [c][g][bh] (131072)
#define WS_DS  262144             // ds[c] (64)
#define WS_HC  262400             // h_contrib -> h_prev: [tile][n][p] (16777216)
#define WS_M   WS_HC              // M aliases HC (M consumed before HC written)

__device__ __forceinline__ float dot4(float4 a, float4 b) {
  return a.x*b.x + a.y*b.y + a.z*b.z + a.w*b.w;
}

// ---------------- K1a: cumsum S + Gram matrix M ----------------
__global__ __launch_bounds__(256) void k_gram(
    const float* __restrict__ X, const float* __restrict__ A,
    const float* __restrict__ Bm, float* __restrict__ ws)
{
  __shared__ float Bs[CSZ][ND+4];
  __shared__ float Xs[CSZ][PD+4];
  __shared__ float Sl[CSZ];

  const int tile = blockIdx.x;
  const int c  = tile & 63;
  const int bh = tile >> 6;
  const int b = bh >> 4, h = bh & 15;
  const int tid = threadIdx.x;

  if (tid < CSZ) Sl[tid] = A[(size_t)(b*SEQ + c*CSZ + tid)*NHD + h];
  __syncthreads();
  if (tid == 0) {
    float acc = 0.f;
    #pragma unroll 1
    for (int t = 0; t < CSZ; ++t) { acc += Sl[t]; Sl[t] = acc; }
  }
  __syncthreads();
  if (tid < CSZ) ws[WS_S + tile*CSZ + tid] = Sl[tid];

  {
    const float* Bbase = Bm + ((size_t)(b*SEQ + c*CSZ)*NHD + h)*ND;
    #pragma unroll
    for (int q = 0; q < 8; ++q) {
      int lin = q*256 + tid;
      int t = lin >> 5, pc = lin & 31;
      float4 v = *(const float4*)(Bbase + (size_t)t*(NHD*ND) + pc*4);
      *(float4*)&Bs[t][pc*4] = v;
    }
    const float* Xbase = X + ((size_t)(b*SEQ + c*CSZ)*NHD + h)*PD;
    #pragma unroll
    for (int q = 0; q < 4; ++q) {
      int lin = q*256 + tid;
      int t = lin >> 4, pc = lin & 15;
      float4 v = *(const float4*)(Xbase + (size_t)t*(NHD*PD) + pc*4);
      *(float4*)&Xs[t][pc*4] = v;
    }
  }
  __syncthreads();

  const int i0 = (tid >> 4)*4, j0 = (tid & 15)*4;
  float gb[4][4] = {}; float gx[4][4] = {};
  for (int k = 0; k < ND; k += 4) {
    float4 av[4], bv[4];
    #pragma unroll
    for (int r = 0; r < 4; ++r) { av[r] = *(float4*)&Bs[i0+r][k]; bv[r] = *(float4*)&Bs[j0+r][k]; }
    #pragma unroll
    for (int r = 0; r < 4; ++r)
      #pragma unroll
      for (int q = 0; q < 4; ++q) gb[r][q] += dot4(av[r], bv[q]);
  }
  for (int k = 0; k < PD; k += 4) {
    float4 av[4], bv[4];
    #pragma unroll
    for (int r = 0; r < 4; ++r) { av[r] = *(float4*)&Xs[i0+r][k]; bv[r] = *(float4*)&Xs[j0+r][k]; }
    #pragma unroll
    for (int r = 0; r < 4; ++r)
      #pragma unroll
      for (int q = 0; q < 4; ++q) gx[r][q] += dot4(av[r], bv[q]);
  }
  float* Mg = ws + WS_M + (size_t)tile*(CSZ*CSZ);
  #pragma unroll
  for (int r = 0; r < 4; ++r) {
    float4 m4 = make_float4(gb[r][0]*gx[r][0]*(1.0f/8192.0f),
                            gb[r][1]*gx[r][1]*(1.0f/8192.0f),
                            gb[r][2]*gx[r][2]*(1.0f/8192.0f),
                            gb[r][3]*gx[r][3]*(1.0f/8192.0f));
    *(float4*)(Mg + (size_t)(i0+r)*CSZ + j0) = m4;
  }
}

// ---------------- K1b: err grid = u_g^T M u_g ----------------
__global__ __launch_bounds__(256) void k_errgrid(float* __restrict__ ws)
{
  __shared__ float Ms[CSZ][CSZ+4];
  __shared__ float Us[GGRID][CSZ+4];
  __shared__ float Zl[CSZ];

  const int tile = blockIdx.x;
  const int c  = tile & 63;
  const int bh = tile >> 6;
  const int tid = threadIdx.x;

  const float* Mg = ws + WS_M + (size_t)tile*(CSZ*CSZ);
  #pragma unroll
  for (int q = 0; q < 4; ++q) {
    int lin = q*256 + tid;
    int row = lin >> 4, c4 = (lin & 15)*4;
    *(float4*)&Ms[row][c4] = *(const float4*)(Mg + (size_t)lin*4);
  }
  if (tid < CSZ) {
    float s63 = ws[WS_S + tile*CSZ + 63];
    Zl[tid] = s63 - ws[WS_S + tile*CSZ + tid];
  }
  __syncthreads();
  #pragma unroll
  for (int q = 0; q < 16; ++q) {
    int idx = q*256 + tid;
    int g = idx >> 6, t = idx & 63;
    Us[g][t] = expf(((float)g*(1.0f/63.0f))*Zl[t]);
  }
  __syncthreads();

  const int g0 = (tid >> 4)*4, t0 = (tid & 15)*4;
  float w[4][4] = {};
  for (int s = 0; s < CSZ; s += 4) {
    float4 uv[4], mv[4];
    #pragma unroll
    for (int r = 0; r < 4; ++r) { uv[r] = *(float4*)&Us[g0+r][s]; mv[r] = *(float4*)&Ms[t0+r][s]; }
    #pragma unroll
    for (int r = 0; r < 4; ++r)
      #pragma unroll
      for (int q = 0; q < 4; ++q) w[r][q] += dot4(uv[r], mv[q]);
  }
  #pragma unroll
  for (int r = 0; r < 4; ++r) {
    float e = w[r][0]*Us[g0+r][t0+0] + w[r][1]*Us[g0+r][t0+1]
            + w[r][2]*Us[g0+r][t0+2] + w[r][3]*Us[g0+r][t0+3];
    e += __shfl_xor(e, 1);
    e += __shfl_xor(e, 2);
    e += __shfl_xor(e, 4);
    e += __shfl_xor(e, 8);
    if ((tid & 15) == 0) ws[WS_EG + (c*GGRID + g0 + r)*BHN + bh] = e;
  }
}

// ---------------- K2: sequential gate chain (one wave) ----------------
__global__ __launch_bounds__(64) void k_gate(
    const float* __restrict__ l2ab, const float* __restrict__ l2b,
    const float* __restrict__ sema, float* __restrict__ ws)
{
  const int lane = threadIdx.x;
  const int h = lane & 15;
  float ab = 0.f, bt = 1.f, ema = 0.f;
  if (lane < NHD) {
    float la = fminf(fmaxf(l2ab[lane], -3.32f), -0.015f);
    ab = 1.0f - exp2f(la);
    float lb = fminf(fmaxf(l2b[lane], -2.0f), 2.0f);
    bt = exp2f(lb);
    ema = sema[lane];
  }
  const float ab_bh = __shfl(ab, h);
  const float bt_bh = __shfl(bt, h);
  float ds_prev = 1.0f;
  if (lane == 0) ws[WS_DS + 0] = 1.0f;
  const float* EG = ws + WS_EG;
  for (int c = 1; c < NCH; ++c) {
    const int j = c - 1;
    float x = ds_prev * 63.0f;
    int ib = (int)floorf(x);
    ib = max(1, min(61, ib));
    float u = x - (float)ib;
    float err = 0.f;
    if (lane < BHN) {
      const float* p = EG + ((size_t)j*GGRID + (ib-1))*BHN + lane;
      float ym1 = p[0], y0 = p[32], y1 = p[64], y2 = p[96];
      err = ym1*(u*(u-1.f)*(u-2.f))*(-1.f/6.f)
          + y0 *((u+1.f)*(u-1.f)*(u-2.f))*(0.5f)
          + y1 *((u+1.f)*u*(u-2.f))*(-0.5f)
          + y2 *((u+1.f)*u*(u-1.f))*(1.f/6.f);
    }
    float e0 = __shfl(err, h);
    float e1 = __shfl(err, 16 + h);
    float ema_new = 0.99f*ema + 0.01f*0.5f*(e0 + e1);
    float emv = __shfl(ema_new, h);
    float oma = 0.f;
    if (lane < BHN) {
      float normalized = err / (emv + 1e-6f);
      float boost = fmaxf(tanhf(bt_bh*normalized), 0.f);
      float alpha = ab_bh + (1.f - ab_bh)*boost;
      alpha = fminf(fmaxf(alpha, 0.01f), 0.999f);
      oma = 1.f - alpha;
    }
    float s = oma;
    s += __shfl_xor(s, 1);  s += __shfl_xor(s, 2);  s += __shfl_xor(s, 4);
    s += __shfl_xor(s, 8);  s += __shfl_xor(s, 16);
    float ds = __shfl(s, 0) * (1.0f/32.0f);
    if (lane < NHD) ema = ema_new;
    if (lane == 0) ws[WS_DS + c] = ds;
    ds_prev = ds;
  }
}

// ---------------- K3: CB, Y_intra, h_contrib ----------------
__global__ __launch_bounds__(256) void k_chunk(
    const float* __restrict__ X, const float* __restrict__ Bm,
    const float* __restrict__ Cm, float* __restrict__ ws,
    float* __restrict__ Y)
{
  __shared__ float Bs[CSZ][ND+4];
  __shared__ float Cs[CSZ][ND+4];
  __shared__ float Xs[CSZ][PD+4];
  __shared__ float Es[CSZ][CSZ+4];
  __shared__ float Acs[CSZ];
  __shared__ float Wl[CSZ];

  const int tile = blockIdx.x;
  const int c  = tile & 63;
  const int bh = tile >> 6;
  const int b = bh >> 4, h = bh & 15;
  const int tid = threadIdx.x;

  const float dsc = ws[WS_DS + c];
  if (tid < CSZ) {
    float sv  = ws[WS_S + tile*CSZ + tid];
    float s63 = ws[WS_S + tile*CSZ + 63];
    Acs[tid] = dsc*sv;
    Wl[tid]  = expf(dsc*(s63 - sv));
  }
  {
    const float* Bbase = Bm + ((size_t)(b*SEQ + c*CSZ)*NHD + h)*ND;
    const float* Cbase = Cm + ((size_t)(b*SEQ + c*CSZ)*NHD + h)*ND;
    #pragma unroll
    for (int q = 0; q < 8; ++q) {
      int lin = q*256 + tid;
      int t = lin >> 5, pc = lin & 31;
      *(float4*)&Bs[t][pc*4] = *(const float4*)(Bbase + (size_t)t*(NHD*ND) + pc*4);
      *(float4*)&Cs[t][pc*4] = *(const float4*)(Cbase + (size_t)t*(NHD*ND) + pc*4);
    }
    const float* Xbase = X + ((size_t)(b*SEQ + c*CSZ)*NHD + h)*PD;
    #pragma unroll
    for (int q = 0; q < 4; ++q) {
      int lin = q*256 + tid;
      int t = lin >> 4, pc = lin & 15;
      *(float4*)&Xs[t][pc*4] = *(const float4*)(Xbase + (size_t)t*(NHD*PD) + pc*4);
    }
  }
  __syncthreads();

  const int i0 = (tid >> 4)*4, j0 = (tid & 15)*4;
  {
    float acc[4][4] = {};
    for (int n = 0; n < ND; n += 4) {
      float4 cv[4], bv[4];
      #pragma unroll
      for (int r = 0; r < 4; ++r) { cv[r] = *(float4*)&Cs[i0+r][n]; bv[r] = *(float4*)&Bs[j0+r][n]; }
      #pragma unroll
      for (int r = 0; r < 4; ++r)
        #pragma unroll
        for (int q = 0; q < 4; ++q) acc[r][q] += dot4(cv[r], bv[q]);
    }
    #pragma unroll
    for (int r = 0; r < 4; ++r) {
      const int i = i0 + r;
      float e[4];
      #pragma unroll
      for (int q = 0; q < 4; ++q) {
        const int jj = j0 + q;
        e[q] = (i >= jj) ? expf(Acs[i]-Acs[jj])*acc[r][q] : 0.f;
      }
      *(float4*)&Es[i][j0] = make_float4(e[0], e[1], e[2], e[3]);
    }
  }
  __syncthreads();

  {
    float ya[4][4] = {};
    for (int j = 0; j < CSZ; j += 4) {
      float4 ev[4], xv[4];
      #pragma unroll
      for (int r = 0; r < 4; ++r) ev[r] = *(float4*)&Es[i0+r][j];
      #pragma unroll
      for (int dj = 0; dj < 4; ++dj) xv[dj] = *(float4*)&Xs[j+dj][j0];
      #pragma unroll
      for (int r = 0; r < 4; ++r) {
        ya[r][0] += ev[r].x*xv[0].x + ev[r].y*xv[1].x + ev[r].z*xv[2].x + ev[r].w*xv[3].x;
        ya[r][1] += ev[r].x*xv[0].y + ev[r].y*xv[1].y + ev[r].z*xv[2].y + ev[r].w*xv[3].y;
        ya[r][2] += ev[r].x*xv[0].z + ev[r].y*xv[1].z + ev[r].z*xv[2].z + ev[r].w*xv[3].z;
        ya[r][3] += ev[r].x*xv[0].w + ev[r].y*xv[1].w + ev[r].z*xv[2].w + ev[r].w*xv[3].w;
      }
    }
    float* Ybase = Y + ((size_t)(b*SEQ + c*CSZ)*NHD + h)*PD;
    #pragma unroll
    for (int r = 0; r < 4; ++r)
      *(float4*)(Ybase + (size_t)(i0+r)*(NHD*PD) + j0) =
          make_float4(ya[r][0], ya[r][1], ya[r][2], ya[r][3]);
  }

  {
    const int n0 = (tid >> 3)*4, p0 = (tid & 7)*8;
    float hc[4][8] = {};
    for (int t = 0; t < CSZ; ++t) {
      const float wt = Wl[t];
      float4 bv = *(float4*)&Bs[t][n0];
      float4 x0 = *(float4*)&Xs[t][p0];
      float4 x1 = *(float4*)&Xs[t][p0+4];
      float xw[8] = { x0.x*wt, x0.y*wt, x0.z*wt, x0.w*wt,
                      x1.x*wt, x1.y*wt, x1.z*wt, x1.w*wt };
      float bl[4] = { bv.x, bv.y, bv.z, bv.w };
      #pragma unroll
      for (int r = 0; r < 4; ++r)
        #pragma unroll
        for (int m = 0; m < 8; ++m) hc[r][m] += bl[r]*xw[m];
    }
    float* hcp = ws + WS_HC + (size_t)tile*(ND*PD);
    #pragma unroll
    for (int r = 0; r < 4; ++r) {
      *(float4*)(hcp + (n0+r)*PD + p0)     = make_float4(hc[r][0],hc[r][1],hc[r][2],hc[r][3]);
      *(float4*)(hcp + (n0+r)*PD + p0 + 4) = make_float4(hc[r][4],hc[r][5],hc[r][6],hc[r][7]);
    }
  }
}

// ---------------- K4: h-state scan (in place: h_contrib -> h_prev) ----------------
__global__ __launch_bounds__(256) void k_scan(float* __restrict__ ws)
{
  __shared__ float dtbl[NCH];
  const int bh = blockIdx.x >> 3, part = blockIdx.x & 7;
  const int tid = threadIdx.x;
  if (tid < NCH) {
    float s63 = ws[WS_S + (bh*NCH + tid)*CSZ + 63];
    dtbl[tid] = expf(ws[WS_DS + tid]*s63);
  }
  __syncthreads();
  float* base = ws + WS_HC + (size_t)bh*(NCH*ND*PD) + part*1024 + tid*4;
  float4 h4 = make_float4(0.f, 0.f, 0.f, 0.f);
  #pragma unroll 1
  for (int c = 0; c < NCH; ++c) {
    float4* p = (float4*)(base + (size_t)c*(ND*PD));
    float4 v = *p;
    *p = h4;
    float dt = dtbl[c];
    h4.x = dt*h4.x + v.x;  h4.y = dt*h4.y + v.y;
    h4.z = dt*h4.z + v.z;  h4.w = dt*h4.w + v.w;
  }
}

// ---------------- K5: Y += dfs o (C @ h_prev) ----------------
__global__ __launch_bounds__(256) void k_inter(
    const float* __restrict__ Cm, float* __restrict__ ws,
    float* __restrict__ Y)
{
  __shared__ float Cs[CSZ][ND+4];
  __shared__ float HPs[ND][PD+4];
  __shared__ float Dfs[CSZ];

  const int tile = blockIdx.x;
  const int c  = tile & 63;
  const int bh = tile >> 6;
  const int b = bh >> 4, h = bh & 15;
  const int tid = threadIdx.x;

  const float dsc = ws[WS_DS + c];
  if (tid < CSZ) Dfs[tid] = expf(dsc*ws[WS_S + tile*CSZ + tid]);
  {
    const float* Cbase = Cm + ((size_t)(b*SEQ + c*CSZ)*NHD + h)*ND;
    #pragma unroll
    for (int q = 0; q < 8; ++q) {
      int lin = q*256 + tid;
      int t = lin >> 5, pc = lin & 31;
      *(float4*)&Cs[t][pc*4] = *(const float4*)(Cbase + (size_t)t*(NHD*ND) + pc*4);
    }
    const float* hp = ws + WS_HC + (size_t)tile*(ND*PD);
    #pragma unroll
    for (int q = 0; q < 8; ++q) {
      int lin = q*256 + tid;
      int n = lin >> 4, c4 = (lin & 15)*4;
      *(float4*)&HPs[n][c4] = *(const float4*)(hp + (size_t)lin*4);
    }
  }
  __syncthreads();

  const int i0 = (tid >> 4)*4, j0 = (tid & 15)*4;
  float acc[4][4] = {};
  for (int n = 0; n < ND; n += 4) {
    float4 cv[4], hv[4];
    #pragma unroll
    for (int r = 0; r < 4; ++r) cv[r] = *(float4*)&Cs[i0+r][n];
    #pragma unroll
    for (int dn = 0; dn < 4; ++dn) hv[dn] = *(float4*)&HPs[n+dn][j0];
    #pragma unroll
    for (int r = 0; r < 4; ++r) {
      acc[r][0] += cv[r].x*hv[0].x + cv[r].y*hv[1].x + cv[r].z*hv[2].x + cv[r].w*hv[3].x;
      acc[r][1] += cv[r].x*hv[0].y + cv[r].y*hv[1].y + cv[r].z*hv[2].y + cv[r].w*hv[3].y;
      acc[r][2] += cv[r].x*hv[0].z + cv[r].y*hv[1].z + cv[r].z*hv[2].z + cv[r].w*hv[3].z;
      acc[r][3] += cv[r].x*hv[0].w + cv[r].y*hv[1].w + cv[r].z*hv[2].w + cv[r].w*hv[3].w;
    }
  }
  float* Ybase = Y + ((size_t)(b*SEQ + c*CSZ)*NHD + h)*PD;
  #pragma unroll
  for (int r = 0; r < 4; ++r) {
    float d = Dfs[i0+r];
    float4* p = (float4*)(Ybase + (size_t)(i0+r)*(NHD*PD) + j0);
    float4 y = *p;
    y.x += d*acc[r][0]; y.y += d*acc[r][1];
    y.z += d*acc[r][2]; y.w += d*acc[r][3];
    *p = y;
  }
}

extern "C" void kernel_launch(void* const* d_in, const int* in_sizes, int n_in,
                              void* d_out, int out_size, void* d_ws, size_t ws_size,
                              hipStream_t stream) {
  const float* X    = (const float*)d_in[0];
  const float* A    = (const float*)d_in[1];
  const float* Bm   = (const float*)d_in[2];
  const float* Cm   = (const float*)d_in[3];
  const float* l2ab = (const float*)d_in[4];
  const float* l2b  = (const float*)d_in[5];
  const float* sema = (const float*)d_in[6];
  float* Y  = (float*)d_out;
  float* ws = (float*)d_ws;

  hipLaunchKernelGGL(k_gram,    dim3(NTILES), dim3(256), 0, stream, X, A, Bm, ws);
  hipLaunchKernelGGL(k_errgrid, dim3(NTILES), dim3(256), 0, stream, ws);
  hipLaunchKernelGGL(k_gate,    dim3(1),      dim3(64),  0, stream, l2ab, l2b, sema, ws);
  hipLaunchKernelGGL(k_chunk,   dim3(NTILES), dim3(256), 0, stream, X, Bm, Cm, ws, Y);
  hipLaunchKernelGGL(k_scan,    dim3(256),    dim3(256), 0, stream, ws);
  hipLaunchKernelGGL(k_inter,   dim3(NTILES), dim3(256), 0, stream, Cm, ws, Y);
}

// Round 3
// 427.230 us; speedup vs baseline: 1.5345x; 1.2527x over previous
//
#include <hip/hip_runtime.h>
#include <math.h>

// ChunkedSurpriseGatedSSD on MI355X — round 3: MFMA (bf16) for k_chunk + k_inter.
// Gate path (k_gram/k_errgrid/k_gate) stays fp32 — its errors amplify through
// exp(ds*S); the Y-producing GEMMs tolerate bf16 (threshold is bf16-floored).
//
// Identity: h_prev - decay_prev*h_before == h_contrib(c-1) =>
// err(c) = u^T M u / (N*P), M = (B B^T) o (X X^T) (decay-independent),
// u_t = exp(ds*(S63-S_t)). Gate chain walked by one wave over a 64-point
// ds-grid of err (cubic interp).

#define CSZ 64
#define NCH 64
#define NHD 16
#define PD  64
#define ND  128
#define BHN 32
#define NTILES 2048
#define GGRID 64
#define SEQ 4096

// ws layout in floats
#define WS_S   0                  // S cumsum: [tile][t]  (131072)
#define WS_EG  131072             // err_grid: [c][g][bh] (131072)
#define WS_DS  262144             // ds[c] (64)
#define WS_HC  262400             // h_contrib -> h_prev: [tile][n][p] (16777216)
#define WS_M   WS_HC              // M aliases HC (M consumed before HC written)

using bf16x8 = __attribute__((ext_vector_type(8))) short;
using f32x4  = __attribute__((ext_vector_type(4))) float;

__device__ __forceinline__ float dot4(float4 a, float4 b) {
  return a.x*b.x + a.y*b.y + a.z*b.z + a.w*b.w;
}

__device__ __forceinline__ short f2bf(float f) {
  union { float f; unsigned u; } v; v.f = f;
  unsigned r = (v.u + 0x7FFFu + ((v.u >> 16) & 1u)) >> 16;
  return (short)r;
}

// ---------------- K1a: cumsum S + Gram matrix M (fp32 — gate path) ----------------
__global__ __launch_bounds__(256) void k_gram(
    const float* __restrict__ X, const float* __restrict__ A,
    const float* __restrict__ Bm, float* __restrict__ ws)
{
  __shared__ float Bs[CSZ][ND+4];
  __shared__ float Xs[CSZ][PD+4];
  __shared__ float Sl[CSZ];

  const int tile = blockIdx.x;
  const int c  = tile & 63;
  const int bh = tile >> 6;
  const int b = bh >> 4, h = bh & 15;
  const int tid = threadIdx.x;

  if (tid < CSZ) Sl[tid] = A[(size_t)(b*SEQ + c*CSZ + tid)*NHD + h];
  __syncthreads();
  if (tid == 0) {
    float acc = 0.f;
    #pragma unroll 1
    for (int t = 0; t < CSZ; ++t) { acc += Sl[t]; Sl[t] = acc; }
  }
  __syncthreads();
  if (tid < CSZ) ws[WS_S + tile*CSZ + tid] = Sl[tid];

  {
    const float* Bbase = Bm + ((size_t)(b*SEQ + c*CSZ)*NHD + h)*ND;
    #pragma unroll
    for (int q = 0; q < 8; ++q) {
      int lin = q*256 + tid;
      int t = lin >> 5, pc = lin & 31;
      *(float4*)&Bs[t][pc*4] = *(const float4*)(Bbase + (size_t)t*(NHD*ND) + pc*4);
    }
    const float* Xbase = X + ((size_t)(b*SEQ + c*CSZ)*NHD + h)*PD;
    #pragma unroll
    for (int q = 0; q < 4; ++q) {
      int lin = q*256 + tid;
      int t = lin >> 4, pc = lin & 15;
      *(float4*)&Xs[t][pc*4] = *(const float4*)(Xbase + (size_t)t*(NHD*PD) + pc*4);
    }
  }
  __syncthreads();

  const int i0 = (tid >> 4)*4, j0 = (tid & 15)*4;
  float gb[4][4] = {}; float gx[4][4] = {};
  for (int k = 0; k < ND; k += 4) {
    float4 av[4], bv[4];
    #pragma unroll
    for (int r = 0; r < 4; ++r) { av[r] = *(float4*)&Bs[i0+r][k]; bv[r] = *(float4*)&Bs[j0+r][k]; }
    #pragma unroll
    for (int r = 0; r < 4; ++r)
      #pragma unroll
      for (int q = 0; q < 4; ++q) gb[r][q] += dot4(av[r], bv[q]);
  }
  for (int k = 0; k < PD; k += 4) {
    float4 av[4], bv[4];
    #pragma unroll
    for (int r = 0; r < 4; ++r) { av[r] = *(float4*)&Xs[i0+r][k]; bv[r] = *(float4*)&Xs[j0+r][k]; }
    #pragma unroll
    for (int r = 0; r < 4; ++r)
      #pragma unroll
      for (int q = 0; q < 4; ++q) gx[r][q] += dot4(av[r], bv[q]);
  }
  float* Mg = ws + WS_M + (size_t)tile*(CSZ*CSZ);
  #pragma unroll
  for (int r = 0; r < 4; ++r) {
    float4 m4 = make_float4(gb[r][0]*gx[r][0]*(1.0f/8192.0f),
                            gb[r][1]*gx[r][1]*(1.0f/8192.0f),
                            gb[r][2]*gx[r][2]*(1.0f/8192.0f),
                            gb[r][3]*gx[r][3]*(1.0f/8192.0f));
    *(float4*)(Mg + (size_t)(i0+r)*CSZ + j0) = m4;
  }
}

// ---------------- K1b: err grid = u_g^T M u_g ----------------
__global__ __launch_bounds__(256) void k_errgrid(float* __restrict__ ws)
{
  __shared__ float Ms[CSZ][CSZ+4];
  __shared__ float Us[GGRID][CSZ+4];
  __shared__ float Zl[CSZ];

  const int tile = blockIdx.x;
  const int c  = tile & 63;
  const int bh = tile >> 6;
  const int tid = threadIdx.x;

  const float* Mg = ws + WS_M + (size_t)tile*(CSZ*CSZ);
  #pragma unroll
  for (int q = 0; q < 4; ++q) {
    int lin = q*256 + tid;
    int row = lin >> 4, c4 = (lin & 15)*4;
    *(float4*)&Ms[row][c4] = *(const float4*)(Mg + (size_t)lin*4);
  }
  if (tid < CSZ) {
    float s63 = ws[WS_S + tile*CSZ + 63];
    Zl[tid] = s63 - ws[WS_S + tile*CSZ + tid];
  }
  __syncthreads();
  #pragma unroll
  for (int q = 0; q < 16; ++q) {
    int idx = q*256 + tid;
    int g = idx >> 6, t = idx & 63;
    Us[g][t] = expf(((float)g*(1.0f/63.0f))*Zl[t]);
  }
  __syncthreads();

  const int g0 = (tid >> 4)*4, t0 = (tid & 15)*4;
  float w[4][4] = {};
  for (int s = 0; s < CSZ; s += 4) {
    float4 uv[4], mv[4];
    #pragma unroll
    for (int r = 0; r < 4; ++r) { uv[r] = *(float4*)&Us[g0+r][s]; mv[r] = *(float4*)&Ms[t0+r][s]; }
    #pragma unroll
    for (int r = 0; r < 4; ++r)
      #pragma unroll
      for (int q = 0; q < 4; ++q) w[r][q] += dot4(uv[r], mv[q]);
  }
  #pragma unroll
  for (int r = 0; r < 4; ++r) {
    float e = w[r][0]*Us[g0+r][t0+0] + w[r][1]*Us[g0+r][t0+1]
            + w[r][2]*Us[g0+r][t0+2] + w[r][3]*Us[g0+r][t0+3];
    e += __shfl_xor(e, 1);
    e += __shfl_xor(e, 2);
    e += __shfl_xor(e, 4);
    e += __shfl_xor(e, 8);
    if ((tid & 15) == 0) ws[WS_EG + (c*GGRID + g0 + r)*BHN + bh] = e;
  }
}

// ---------------- K2: sequential gate chain (one wave) ----------------
__global__ __launch_bounds__(64) void k_gate(
    const float* __restrict__ l2ab, const float* __restrict__ l2b,
    const float* __restrict__ sema, float* __restrict__ ws)
{
  const int lane = threadIdx.x;
  const int h = lane & 15;
  float ab = 0.f, bt = 1.f, ema = 0.f;
  if (lane < NHD) {
    float la = fminf(fmaxf(l2ab[lane], -3.32f), -0.015f);
    ab = 1.0f - exp2f(la);
    float lb = fminf(fmaxf(l2b[lane], -2.0f), 2.0f);
    bt = exp2f(lb);
    ema = sema[lane];
  }
  const float ab_bh = __shfl(ab, h);
  const float bt_bh = __shfl(bt, h);
  float ds_prev = 1.0f;
  if (lane == 0) ws[WS_DS + 0] = 1.0f;
  const float* EG = ws + WS_EG;
  for (int c = 1; c < NCH; ++c) {
    const int j = c - 1;
    float x = ds_prev * 63.0f;
    int ib = (int)floorf(x);
    ib = max(1, min(61, ib));
    float u = x - (float)ib;
    float err = 0.f;
    if (lane < BHN) {
      const float* p = EG + ((size_t)j*GGRID + (ib-1))*BHN + lane;
      float ym1 = p[0], y0 = p[32], y1 = p[64], y2 = p[96];
      err = ym1*(u*(u-1.f)*(u-2.f))*(-1.f/6.f)
          + y0 *((u+1.f)*(u-1.f)*(u-2.f))*(0.5f)
          + y1 *((u+1.f)*u*(u-2.f))*(-0.5f)
          + y2 *((u+1.f)*u*(u-1.f))*(1.f/6.f);
    }
    float e0 = __shfl(err, h);
    float e1 = __shfl(err, 16 + h);
    float ema_new = 0.99f*ema + 0.01f*0.5f*(e0 + e1);
    float emv = __shfl(ema_new, h);
    float oma = 0.f;
    if (lane < BHN) {
      float normalized = err / (emv + 1e-6f);
      float boost = fmaxf(tanhf(bt_bh*normalized), 0.f);
      float alpha = ab_bh + (1.f - ab_bh)*boost;
      alpha = fminf(fmaxf(alpha, 0.01f), 0.999f);
      oma = 1.f - alpha;
    }
    float s = oma;
    s += __shfl_xor(s, 1);  s += __shfl_xor(s, 2);  s += __shfl_xor(s, 4);
    s += __shfl_xor(s, 8);  s += __shfl_xor(s, 16);
    float ds = __shfl(s, 0) * (1.0f/32.0f);
    if (lane < NHD) ema = ema_new;
    if (lane == 0) ws[WS_DS + c] = ds;
    ds_prev = ds;
  }
}

// ---------------- K3: MFMA — CB, Y_intra, h_contrib ----------------
// LDS bf16: Cs/Bs row-major [t][n] (stride 136), BsTw [n][t]*w (stride 72),
// XsT [p][t] (stride 72), Es [i][j] (stride 72). 72.2 KB -> 2 blocks/CU.
__global__ __launch_bounds__(256, 2) void k_chunk(
    const float* __restrict__ X, const float* __restrict__ Bm,
    const float* __restrict__ Cm, float* __restrict__ ws,
    float* __restrict__ Y)
{
  __shared__ short Cs[64*136];
  __shared__ short Bs[64*136];
  __shared__ short BsTw[128*72];
  __shared__ short XsT[64*72];
  __shared__ short Es[64*72];
  __shared__ float Acs[CSZ];
  __shared__ float Wl[CSZ];

  const int tile = blockIdx.x;
  const int c  = tile & 63;
  const int bh = tile >> 6;
  const int b = bh >> 4, h = bh & 15;
  const int tid = threadIdx.x;

  const float dsc = ws[WS_DS + c];
  if (tid < CSZ) {
    float sv  = ws[WS_S + tile*CSZ + tid];
    float s63 = ws[WS_S + tile*CSZ + 63];
    Acs[tid] = dsc*sv;
    Wl[tid]  = expf(dsc*(s63 - sv));
  }
  __syncthreads();

  const float* Bbase = Bm + ((size_t)(b*SEQ + c*CSZ)*NHD + h)*ND;
  const float* Cbase = Cm + ((size_t)(b*SEQ + c*CSZ)*NHD + h)*ND;
  const float* Xbase = X  + ((size_t)(b*SEQ + c*CSZ)*NHD + h)*PD;
  #pragma unroll
  for (int qq = 0; qq < 8; ++qq) {
    int lin = qq*256 + tid;
    int t = lin >> 5, n4 = (lin & 31)*4;
    float4 cv = *(const float4*)(Cbase + (size_t)t*(NHD*ND) + n4);
    short4 cs4; cs4.x=f2bf(cv.x); cs4.y=f2bf(cv.y); cs4.z=f2bf(cv.z); cs4.w=f2bf(cv.w);
    *(short4*)&Cs[t*136 + n4] = cs4;
    float4 bv = *(const float4*)(Bbase + (size_t)t*(NHD*ND) + n4);
    short4 bs4; bs4.x=f2bf(bv.x); bs4.y=f2bf(bv.y); bs4.z=f2bf(bv.z); bs4.w=f2bf(bv.w);
    *(short4*)&Bs[t*136 + n4] = bs4;
    float wt = Wl[t];
    BsTw[(n4+0)*72 + t] = f2bf(bv.x*wt);
    BsTw[(n4+1)*72 + t] = f2bf(bv.y*wt);
    BsTw[(n4+2)*72 + t] = f2bf(bv.z*wt);
    BsTw[(n4+3)*72 + t] = f2bf(bv.w*wt);
  }
  #pragma unroll
  for (int qq = 0; qq < 4; ++qq) {
    int lin = qq*256 + tid;
    int t = lin >> 4, p4 = (lin & 15)*4;
    float4 xv = *(const float4*)(Xbase + (size_t)t*(NHD*PD) + p4);
    XsT[(p4+0)*72 + t] = f2bf(xv.x);
    XsT[(p4+1)*72 + t] = f2bf(xv.y);
    XsT[(p4+2)*72 + t] = f2bf(xv.z);
    XsT[(p4+3)*72 + t] = f2bf(xv.w);
  }
  __syncthreads();

  const int w = tid >> 6;
  const int lane = tid & 63;
  const int m = lane & 15, q = lane >> 4;

  // GEMM1: CB[i][j], wave w owns i-slab [16w,16w+16)
  f32x4 acc0 = {0.f,0.f,0.f,0.f}, acc1 = acc0, acc2 = acc0, acc3 = acc0;
  #pragma unroll
  for (int kk = 0; kk < 4; ++kk) {
    bf16x8 af = *(bf16x8*)&Cs[(w*16+m)*136 + kk*32 + q*8];
    bf16x8 b0 = *(bf16x8*)&Bs[( 0+m)*136 + kk*32 + q*8];
    bf16x8 b1 = *(bf16x8*)&Bs[(16+m)*136 + kk*32 + q*8];
    bf16x8 b2 = *(bf16x8*)&Bs[(32+m)*136 + kk*32 + q*8];
    bf16x8 b3 = *(bf16x8*)&Bs[(48+m)*136 + kk*32 + q*8];
    acc0 = __builtin_amdgcn_mfma_f32_16x16x32_bf16(af, b0, acc0, 0,0,0);
    acc1 = __builtin_amdgcn_mfma_f32_16x16x32_bf16(af, b1, acc1, 0,0,0);
    acc2 = __builtin_amdgcn_mfma_f32_16x16x32_bf16(af, b2, acc2, 0,0,0);
    acc3 = __builtin_amdgcn_mfma_f32_16x16x32_bf16(af, b3, acc3, 0,0,0);
  }
  // E = mask * exp(Acs_i - Acs_j) * CB -> Es (bf16), same-wave rows
  {
    f32x4 accs[4] = {acc0, acc1, acc2, acc3};
    #pragma unroll
    for (int ct = 0; ct < 4; ++ct) {
      int j = ct*16 + m;
      float aj = Acs[j];
      #pragma unroll
      for (int r = 0; r < 4; ++r) {
        int i = w*16 + q*4 + r;
        float v = (i >= j) ? expf(Acs[i]-aj)*accs[ct][r] : 0.f;
        Es[i*72 + j] = f2bf(v);
      }
    }
  }

  // GEMM3: h_contrib[n][p] = sum_t B[t][n]*w_t*X[t][p]; wave w owns n-tiles {2w,2w+1}
  f32x4 h00={0.f,0.f,0.f,0.f}, h01=h00, h02=h00, h03=h00;
  f32x4 h10=h00, h11=h00, h12=h00, h13=h00;
  #pragma unroll
  for (int kk = 0; kk < 2; ++kk) {
    bf16x8 a0 = *(bf16x8*)&BsTw[((2*w+0)*16+m)*72 + kk*32 + q*8];
    bf16x8 a1 = *(bf16x8*)&BsTw[((2*w+1)*16+m)*72 + kk*32 + q*8];
    bf16x8 x0 = *(bf16x8*)&XsT[( 0+m)*72 + kk*32 + q*8];
    bf16x8 x1 = *(bf16x8*)&XsT[(16+m)*72 + kk*32 + q*8];
    bf16x8 x2 = *(bf16x8*)&XsT[(32+m)*72 + kk*32 + q*8];
    bf16x8 x3 = *(bf16x8*)&XsT[(48+m)*72 + kk*32 + q*8];
    h00 = __builtin_amdgcn_mfma_f32_16x16x32_bf16(a0, x0, h00, 0,0,0);
    h01 = __builtin_amdgcn_mfma_f32_16x16x32_bf16(a0, x1, h01, 0,0,0);
    h02 = __builtin_amdgcn_mfma_f32_16x16x32_bf16(a0, x2, h02, 0,0,0);
    h03 = __builtin_amdgcn_mfma_f32_16x16x32_bf16(a0, x3, h03, 0,0,0);
    h10 = __builtin_amdgcn_mfma_f32_16x16x32_bf16(a1, x0, h10, 0,0,0);
    h11 = __builtin_amdgcn_mfma_f32_16x16x32_bf16(a1, x1, h11, 0,0,0);
    h12 = __builtin_amdgcn_mfma_f32_16x16x32_bf16(a1, x2, h12, 0,0,0);
    h13 = __builtin_amdgcn_mfma_f32_16x16x32_bf16(a1, x3, h13, 0,0,0);
  }

  // GEMM2: Y_intra[i][p] = sum_j E[i][j]*X[j][p] (Es rows written by this wave)
  f32x4 y0={0.f,0.f,0.f,0.f}, y1=y0, y2=y0, y3=y0;
  #pragma unroll
  for (int kk = 0; kk < 2; ++kk) {
    bf16x8 ef = *(bf16x8*)&Es[(w*16+m)*72 + kk*32 + q*8];
    bf16x8 x0 = *(bf16x8*)&XsT[( 0+m)*72 + kk*32 + q*8];
    bf16x8 x1 = *(bf16x8*)&XsT[(16+m)*72 + kk*32 + q*8];
    bf16x8 x2 = *(bf16x8*)&XsT[(32+m)*72 + kk*32 + q*8];
    bf16x8 x3 = *(bf16x8*)&XsT[(48+m)*72 + kk*32 + q*8];
    y0 = __builtin_amdgcn_mfma_f32_16x16x32_bf16(ef, x0, y0, 0,0,0);
    y1 = __builtin_amdgcn_mfma_f32_16x16x32_bf16(ef, x1, y1, 0,0,0);
    y2 = __builtin_amdgcn_mfma_f32_16x16x32_bf16(ef, x2, y2, 0,0,0);
    y3 = __builtin_amdgcn_mfma_f32_16x16x32_bf16(ef, x3, y3, 0,0,0);
  }

  // Epilogue: Y_intra
  {
    float* Ybase = Y + ((size_t)(b*SEQ + c*CSZ)*NHD + h)*PD;
    f32x4 ys[4] = {y0, y1, y2, y3};
    #pragma unroll
    for (int r = 0; r < 4; ++r) {
      int i = w*16 + q*4 + r;
      #pragma unroll
      for (int ct = 0; ct < 4; ++ct)
        Ybase[(size_t)i*(NHD*PD) + ct*16 + m] = ys[ct][r];
    }
  }
  // Epilogue: h_contrib -> ws
  {
    float* hcp = ws + WS_HC + (size_t)tile*(ND*PD);
    f32x4 hs[2][4] = {{h00,h01,h02,h03},{h10,h11,h12,h13}};
    #pragma unroll
    for (int nt = 0; nt < 2; ++nt)
      #pragma unroll
      for (int r = 0; r < 4; ++r) {
        int n = (2*w+nt)*16 + q*4 + r;
        #pragma unroll
        for (int pt = 0; pt < 4; ++pt)
          hcp[n*PD + pt*16 + m] = hs[nt][pt][r];
      }
  }
}

// ---------------- K4: h-state scan (in place: h_contrib -> h_prev) ----------------
__global__ __launch_bounds__(256) void k_scan(float* __restrict__ ws)
{
  __shared__ float dtbl[NCH];
  const int bh = blockIdx.x >> 3, part = blockIdx.x & 7;
  const int tid = threadIdx.x;
  if (tid < NCH) {
    float s63 = ws[WS_S + (bh*NCH + tid)*CSZ + 63];
    dtbl[tid] = expf(ws[WS_DS + tid]*s63);
  }
  __syncthreads();
  float* base = ws + WS_HC + (size_t)bh*(NCH*ND*PD) + part*1024 + tid*4;
  float4 h4 = make_float4(0.f, 0.f, 0.f, 0.f);
  #pragma unroll 1
  for (int c = 0; c < NCH; ++c) {
    float4* p = (float4*)(base + (size_t)c*(ND*PD));
    float4 v = *p;
    *p = h4;
    float dt = dtbl[c];
    h4.x = dt*h4.x + v.x;  h4.y = dt*h4.y + v.y;
    h4.z = dt*h4.z + v.z;  h4.w = dt*h4.w + v.w;
  }
}

// ---------------- K5: MFMA — Y += dfs o (C @ h_prev) ----------------
__global__ __launch_bounds__(256, 4) void k_inter(
    const float* __restrict__ Cm, float* __restrict__ ws,
    float* __restrict__ Y)
{
  __shared__ short Cs[64*136];   // C[t][n]
  __shared__ short HsT[64*136];  // h^T: [p][n]
  __shared__ float Dfs[CSZ];

  const int tile = blockIdx.x;
  const int c  = tile & 63;
  const int bh = tile >> 6;
  const int b = bh >> 4, h = bh & 15;
  const int tid = threadIdx.x;

  const float dsc = ws[WS_DS + c];
  if (tid < CSZ) Dfs[tid] = expf(dsc*ws[WS_S + tile*CSZ + tid]);

  const float* Cbase = Cm + ((size_t)(b*SEQ + c*CSZ)*NHD + h)*ND;
  const float* hp = ws + WS_HC + (size_t)tile*(ND*PD);
  #pragma unroll
  for (int qq = 0; qq < 8; ++qq) {
    int lin = qq*256 + tid;
    int t = lin >> 5, n4 = (lin & 31)*4;
    float4 cv = *(const float4*)(Cbase + (size_t)t*(NHD*ND) + n4);
    short4 cs4; cs4.x=f2bf(cv.x); cs4.y=f2bf(cv.y); cs4.z=f2bf(cv.z); cs4.w=f2bf(cv.w);
    *(short4*)&Cs[t*136 + n4] = cs4;
    int n = lin >> 4, p4 = (lin & 15)*4;
    float4 hv = *(const float4*)(hp + (size_t)lin*4);
    HsT[(p4+0)*136 + n] = f2bf(hv.x);
    HsT[(p4+1)*136 + n] = f2bf(hv.y);
    HsT[(p4+2)*136 + n] = f2bf(hv.z);
    HsT[(p4+3)*136 + n] = f2bf(hv.w);
  }
  __syncthreads();

  const int w = tid >> 6;
  const int lane = tid & 63;
  const int m = lane & 15, q = lane >> 4;

  f32x4 a0 = {0.f,0.f,0.f,0.f}, a1 = a0, a2 = a0, a3 = a0;
  #pragma unroll
  for (int kk = 0; kk < 4; ++kk) {
    bf16x8 cf = *(bf16x8*)&Cs[(w*16+m)*136 + kk*32 + q*8];
    bf16x8 hb0 = *(bf16x8*)&HsT[( 0+m)*136 + kk*32 + q*8];
    bf16x8 hb1 = *(bf16x8*)&HsT[(16+m)*136 + kk*32 + q*8];
    bf16x8 hb2 = *(bf16x8*)&HsT[(32+m)*136 + kk*32 + q*8];
    bf16x8 hb3 = *(bf16x8*)&HsT[(48+m)*136 + kk*32 + q*8];
    a0 = __builtin_amdgcn_mfma_f32_16x16x32_bf16(cf, hb0, a0, 0,0,0);
    a1 = __builtin_amdgcn_mfma_f32_16x16x32_bf16(cf, hb1, a1, 0,0,0);
    a2 = __builtin_amdgcn_mfma_f32_16x16x32_bf16(cf, hb2, a2, 0,0,0);
    a3 = __builtin_amdgcn_mfma_f32_16x16x32_bf16(cf, hb3, a3, 0,0,0);
  }

  float* Ybase = Y + ((size_t)(b*SEQ + c*CSZ)*NHD + h)*PD;
  f32x4 as[4] = {a0, a1, a2, a3};
  #pragma unroll
  for (int r = 0; r < 4; ++r) {
    int i = w*16 + q*4 + r;
    float d = Dfs[i];
    #pragma unroll
    for (int ct = 0; ct < 4; ++ct) {
      size_t idx = (size_t)i*(NHD*PD) + ct*16 + m;
      Ybase[idx] += d*as[ct][r];
    }
  }
}

extern "C" void kernel_launch(void* const* d_in, const int* in_sizes, int n_in,
                              void* d_out, int out_size, void* d_ws, size_t ws_size,
                              hipStream_t stream) {
  const float* X    = (const float*)d_in[0];
  const float* A    = (const float*)d_in[1];
  const float* Bm   = (const float*)d_in[2];
  const float* Cm   = (const float*)d_in[3];
  const float* l2ab = (const float*)d_in[4];
  const float* l2b  = (const float*)d_in[5];
  const float* sema = (const float*)d_in[6];
  float* Y  = (float*)d_out;
  float* ws = (float*)d_ws;

  hipLaunchKernelGGL(k_gram,    dim3(NTILES), dim3(256), 0, stream, X, A, Bm, ws);
  hipLaunchKernelGGL(k_errgrid, dim3(NTILES), dim3(256), 0, stream, ws);
  hipLaunchKernelGGL(k_gate,    dim3(1),      dim3(64),  0, stream, l2ab, l2b, sema, ws);
  hipLaunchKernelGGL(k_chunk,   dim3(NTILES), dim3(256), 0, stream, X, Bm, Cm, ws, Y);
  hipLaunchKernelGGL(k_scan,    dim3(256),    dim3(256), 0, stream, ws);
  hipLaunchKernelGGL(k_inter,   dim3(NTILES), dim3(256), 0, stream, Cm, ws, Y);
}